// Round 4
// baseline (672.986 us; speedup 1.0000x reference)
//
#include <hip/hip_runtime.h>
#include <hip/hip_bf16.h>
#include <hip/hip_cooperative_groups.h>
#include <cmath>

namespace cg = cooperative_groups;

// Problem constants (fixed by setup_inputs)
constexpr int S = 128;   // num_states
constexpr int C = 32;    // num_chains
constexpr int N = 4096;  // num_nodes
constexpr int T = 512;   // num_iters

// Output layout (flat float32, concatenated in reference return order)
constexpr size_t OFF1 = 0;                          // log_observed_state_probs  [T,N]
constexpr size_t OFF2 = OFF1 + (size_t)T * N;       // log_observed_state_probs_ [T,C,N]
constexpr size_t OFF3 = OFF2 + (size_t)T * C * N;   // log_hidden_state_probs   [T,C,S]
constexpr size_t OFF4 = OFF3 + (size_t)T * C * S;   // log_emission             [S,N]
constexpr size_t OFF5 = OFF4 + (size_t)S * N;       // log_chain_weights        [T,C]

typedef __bf16 bf16x8 __attribute__((ext_vector_type(8)));
typedef float floatx4 __attribute__((ext_vector_type(4)));
typedef float floatx16 __attribute__((ext_vector_type(16)));

__device__ __forceinline__ void split_bf16(float p, __bf16& hi, __bf16& lo) {
    hi = (__bf16)p;
    lo = (__bf16)(p - (float)hi);
}

// ---------------------------------------------------------------------------
// Fused softmax kernel, one launch, 352 blocks x 256 threads:
//   [0,128)   emission rows (4096 cols): log->out4, bf16 transposed -> pET[N,S]
//   [128,256) transition rows (128 cols): hi/lo pair row-major (R) + transposed (T)
//   [256,288) init rows (128 cols): log->out3[t=0], hi/lo pair -> Hhi/Hlo[t=0]
//   [288,352) chain weights, 8 rows/block of 32 cols: log->out5, fp32 -> pcw
// ---------------------------------------------------------------------------
__global__ __launch_bounds__(256) void fused_softmax_kernel(
        const float* __restrict__ emis, const float* __restrict__ cw,
        const float* __restrict__ trans, const float* __restrict__ init,
        float* __restrict__ out3, float* __restrict__ out4, float* __restrict__ out5,
        __bf16* __restrict__ pET, float* __restrict__ pcw,
        __bf16* __restrict__ Rhi, __bf16* __restrict__ Rlo,
        __bf16* __restrict__ Thi, __bf16* __restrict__ Tlo,
        __bf16* __restrict__ Hhi, __bf16* __restrict__ Hlo) {
    const int b = blockIdx.x;
    const int tid = threadIdx.x;

    if (b >= 288) {   // ---- chain weights: 8 rows of 32 per block ----
        const int row = (b - 288) * 8 + (tid >> 5);
        const int j = tid & 31;
        const float v = cw[(size_t)row * C + j];
        float m = v;
#pragma unroll
        for (int o = 16; o > 0; o >>= 1) m = fmaxf(m, __shfl_xor(m, o, 64));
        float s = __expf(v - m);
#pragma unroll
        for (int o = 16; o > 0; o >>= 1) s += __shfl_xor(s, o, 64);
        const float lv = v - m - __logf(s);
        out5[(size_t)row * C + j] = lv;
        pcw[(size_t)row * C + j] = __expf(lv);
        return;
    }

    const float* x;
    int cols, row;
    if (b < 128)      { row = b;       cols = N; x = emis  + (size_t)row * N; }
    else if (b < 256) { row = b - 128; cols = S; x = trans + (size_t)row * S; }
    else              { row = b - 256; cols = S; x = init  + (size_t)row * S; }

    __shared__ float sm[4];
    __shared__ float ss[4];

    float m = -INFINITY;
    for (int j = tid; j < cols; j += 256) m = fmaxf(m, x[j]);
#pragma unroll
    for (int o = 32; o > 0; o >>= 1) m = fmaxf(m, __shfl_xor(m, o, 64));
    const int wid = tid >> 6;
    if ((tid & 63) == 0) sm[wid] = m;
    __syncthreads();
    m = fmaxf(fmaxf(sm[0], sm[1]), fmaxf(sm[2], sm[3]));

    float s = 0.f;
    for (int j = tid; j < cols; j += 256) s += __expf(x[j] - m);
#pragma unroll
    for (int o = 32; o > 0; o >>= 1) s += __shfl_xor(s, o, 64);
    if ((tid & 63) == 0) ss[wid] = s;
    __syncthreads();
    s = ss[0] + ss[1] + ss[2] + ss[3];
    const float lse = m + __logf(s);

    for (int j = tid; j < cols; j += 256) {
        const float v = x[j] - lse;
        const float p = __expf(v);
        if (b < 128) {
            out4[(size_t)row * N + j] = v;
            pET[(size_t)j * S + row] = (__bf16)p;
        } else if (b < 256) {
            __bf16 hi, lo; split_bf16(p, hi, lo);
            Rhi[(size_t)row * S + j] = hi; Rlo[(size_t)row * S + j] = lo;
            Thi[(size_t)j * S + row] = hi; Tlo[(size_t)j * S + row] = lo;
        } else {
            out3[((size_t)0 * C + row) * S + j] = v;
            __bf16 hi, lo; split_bf16(p, hi, lo);
            Hhi[(size_t)row * S + j] = hi; Hlo[(size_t)row * S + j] = lo;
        }
    }
}

// ---------------------------------------------------------------------------
// All 9 H-doubling rounds in ONE cooperative kernel (grid = 264 blocks).
// Round r (m = 2^(r-1)):
//   blocks [0, count):       H_{m+b} = H_b * P^m   (+ pair store + log->out3)
//   blocks [count, count+8): P^{2m}  = P^m * P^m   (16 rows each, both layouts)
// hi/lo bf16 pair MFMA (3 MFMAs per product -> ~fp32 accuracy).
// grid.sync() between rounds replaces 9 kernel launches.
// ---------------------------------------------------------------------------
__global__ __launch_bounds__(256) void chain_coop_kernel(
        __bf16* __restrict__ R0hi, __bf16* __restrict__ R0lo,
        __bf16* __restrict__ T0hi, __bf16* __restrict__ T0lo,
        __bf16* __restrict__ R1hi, __bf16* __restrict__ R1lo,
        __bf16* __restrict__ T1hi, __bf16* __restrict__ T1lo,
        __bf16* __restrict__ Hhi, __bf16* __restrict__ Hlo,
        float* __restrict__ out3) {
    cg::grid_group grid = cg::this_grid();
    const int b = blockIdx.x;
    const int w = threadIdx.x >> 6;
    const int lane = threadIdx.x & 63;
    const int lr = lane & 15;
    const int quad = lane >> 4;

    for (int r = 1; r <= 9; r++) {
        const int m = 1 << (r - 1);
        const int count = (m < T - m) ? m : (T - m);
        const bool src0 = ((r - 1) & 1) == 0;
        const __bf16* Rhi = src0 ? R0hi : R1hi;
        const __bf16* Rlo = src0 ? R0lo : R1lo;
        const __bf16* Thi = src0 ? T0hi : T1hi;
        const __bf16* Tlo = src0 ? T0lo : T1lo;
        __bf16* Rnhi = src0 ? R1hi : R0hi;
        __bf16* Rnlo = src0 ? R1lo : R0lo;
        __bf16* Tnhi = src0 ? T1hi : T0hi;
        __bf16* Tnlo = src0 ? T1lo : T0lo;

        if (b < count) {
            const __bf16* Ahi = Hhi + (size_t)b * C * S;
            const __bf16* Alo = Hlo + (size_t)b * C * S;
            floatx4 acc[2][2];
#pragma unroll
            for (int mt = 0; mt < 2; mt++)
#pragma unroll
                for (int nt = 0; nt < 2; nt++) acc[mt][nt] = (floatx4)0.f;

#pragma unroll
            for (int kt = 0; kt < 4; kt++) {
                const int ko = kt * 32 + quad * 8;
                const bf16x8 ah0 = *reinterpret_cast<const bf16x8*>(&Ahi[(size_t)lr * S + ko]);
                const bf16x8 ah1 = *reinterpret_cast<const bf16x8*>(&Ahi[(size_t)(16 + lr) * S + ko]);
                const bf16x8 al0 = *reinterpret_cast<const bf16x8*>(&Alo[(size_t)lr * S + ko]);
                const bf16x8 al1 = *reinterpret_cast<const bf16x8*>(&Alo[(size_t)(16 + lr) * S + ko]);
                const bf16x8 bh0 = *reinterpret_cast<const bf16x8*>(&Thi[(size_t)(w * 32 + lr) * S + ko]);
                const bf16x8 bh1 = *reinterpret_cast<const bf16x8*>(&Thi[(size_t)(w * 32 + 16 + lr) * S + ko]);
                const bf16x8 bl0 = *reinterpret_cast<const bf16x8*>(&Tlo[(size_t)(w * 32 + lr) * S + ko]);
                const bf16x8 bl1 = *reinterpret_cast<const bf16x8*>(&Tlo[(size_t)(w * 32 + 16 + lr) * S + ko]);
                acc[0][0] = __builtin_amdgcn_mfma_f32_16x16x32_bf16(ah0, bh0, acc[0][0], 0, 0, 0);
                acc[0][0] = __builtin_amdgcn_mfma_f32_16x16x32_bf16(ah0, bl0, acc[0][0], 0, 0, 0);
                acc[0][0] = __builtin_amdgcn_mfma_f32_16x16x32_bf16(al0, bh0, acc[0][0], 0, 0, 0);
                acc[0][1] = __builtin_amdgcn_mfma_f32_16x16x32_bf16(ah0, bh1, acc[0][1], 0, 0, 0);
                acc[0][1] = __builtin_amdgcn_mfma_f32_16x16x32_bf16(ah0, bl1, acc[0][1], 0, 0, 0);
                acc[0][1] = __builtin_amdgcn_mfma_f32_16x16x32_bf16(al0, bh1, acc[0][1], 0, 0, 0);
                acc[1][0] = __builtin_amdgcn_mfma_f32_16x16x32_bf16(ah1, bh0, acc[1][0], 0, 0, 0);
                acc[1][0] = __builtin_amdgcn_mfma_f32_16x16x32_bf16(ah1, bl0, acc[1][0], 0, 0, 0);
                acc[1][0] = __builtin_amdgcn_mfma_f32_16x16x32_bf16(al1, bh0, acc[1][0], 0, 0, 0);
                acc[1][1] = __builtin_amdgcn_mfma_f32_16x16x32_bf16(ah1, bh1, acc[1][1], 0, 0, 0);
                acc[1][1] = __builtin_amdgcn_mfma_f32_16x16x32_bf16(ah1, bl1, acc[1][1], 0, 0, 0);
                acc[1][1] = __builtin_amdgcn_mfma_f32_16x16x32_bf16(al1, bh1, acc[1][1], 0, 0, 0);
            }

            const size_t t = (size_t)m + b;
#pragma unroll
            for (int mt = 0; mt < 2; mt++) {
#pragma unroll
                for (int nt = 0; nt < 2; nt++) {
#pragma unroll
                    for (int reg = 0; reg < 4; reg++) {
                        const int c = mt * 16 + quad * 4 + reg;
                        const int n = w * 32 + nt * 16 + lr;
                        const float p = acc[mt][nt][reg];
                        __bf16 hi, lo; split_bf16(p, hi, lo);
                        Hhi[(t * C + c) * S + n] = hi;
                        Hlo[(t * C + c) * S + n] = lo;
                        out3[(t * C + c) * S + n] = __logf(p);
                    }
                }
            }
        } else if (b < count + 8 && r < 9) {
            const int rb = b - count;
            floatx4 acc[2];
            acc[0] = (floatx4)0.f; acc[1] = (floatx4)0.f;
#pragma unroll
            for (int kt = 0; kt < 4; kt++) {
                const int ko = kt * 32 + quad * 8;
                const bf16x8 ah = *reinterpret_cast<const bf16x8*>(&Rhi[(size_t)(rb * 16 + lr) * S + ko]);
                const bf16x8 al = *reinterpret_cast<const bf16x8*>(&Rlo[(size_t)(rb * 16 + lr) * S + ko]);
                const bf16x8 bh0 = *reinterpret_cast<const bf16x8*>(&Thi[(size_t)(w * 32 + lr) * S + ko]);
                const bf16x8 bh1 = *reinterpret_cast<const bf16x8*>(&Thi[(size_t)(w * 32 + 16 + lr) * S + ko]);
                const bf16x8 bl0 = *reinterpret_cast<const bf16x8*>(&Tlo[(size_t)(w * 32 + lr) * S + ko]);
                const bf16x8 bl1 = *reinterpret_cast<const bf16x8*>(&Tlo[(size_t)(w * 32 + 16 + lr) * S + ko]);
                acc[0] = __builtin_amdgcn_mfma_f32_16x16x32_bf16(ah, bh0, acc[0], 0, 0, 0);
                acc[0] = __builtin_amdgcn_mfma_f32_16x16x32_bf16(ah, bl0, acc[0], 0, 0, 0);
                acc[0] = __builtin_amdgcn_mfma_f32_16x16x32_bf16(al, bh0, acc[0], 0, 0, 0);
                acc[1] = __builtin_amdgcn_mfma_f32_16x16x32_bf16(ah, bh1, acc[1], 0, 0, 0);
                acc[1] = __builtin_amdgcn_mfma_f32_16x16x32_bf16(ah, bl1, acc[1], 0, 0, 0);
                acc[1] = __builtin_amdgcn_mfma_f32_16x16x32_bf16(al, bh1, acc[1], 0, 0, 0);
            }
#pragma unroll
            for (int nt = 0; nt < 2; nt++) {
#pragma unroll
                for (int reg = 0; reg < 4; reg++) {
                    const int row = rb * 16 + quad * 4 + reg;
                    const int col = w * 32 + nt * 16 + lr;
                    const float p = acc[nt][reg];
                    __bf16 hi, lo; split_bf16(p, hi, lo);
                    Rnhi[(size_t)row * S + col] = hi; Rnlo[(size_t)row * S + col] = lo;
                    Tnhi[(size_t)col * S + row] = hi; Tnlo[(size_t)col * S + row] = lo;
                }
            }
        }
        grid.sync();
    }
}

// ---------------------------------------------------------------------------
// Observation GEMM via 32x32x16 MFMA + fused epilogue.
// Block: one t, 256 n-cols; 4 waves, each wave a 32(c) x 64(n) tile as two
// 32x32 accumulators. C/D layout: col=lane&31, row=(reg&3)+8*(reg>>2)+4*half.
// out2 stores are 128B-contiguous segments, nontemporal (never re-read).
// ---------------------------------------------------------------------------
__global__ __launch_bounds__(256) void obs_mfma_kernel(
        const __bf16* __restrict__ Hb,    // [T,C,S] (hi plane)
        const __bf16* __restrict__ pET,   // [N,S]
        const float* __restrict__ pcw,    // [T,C]
        float* __restrict__ out1,
        float* __restrict__ out2) {
    const int t = blockIdx.y;
    const int w = threadIdx.x >> 6;
    const int lane = threadIdx.x & 63;
    const int l31 = lane & 31;
    const int half = lane >> 5;
    const int nbase = blockIdx.x * 256 + w * 64;

    __shared__ float sw[C];
    if (threadIdx.x < C) sw[threadIdx.x] = pcw[(size_t)t * C + threadIdx.x];
    __syncthreads();

    const __bf16* A = Hb + (size_t)t * C * S;

    floatx16 acc0 = (floatx16)0.f;
    floatx16 acc1 = (floatx16)0.f;

#pragma unroll
    for (int ks = 0; ks < 8; ks++) {
        const int ko = ks * 16 + half * 8;
        const bf16x8 a  = *reinterpret_cast<const bf16x8*>(&A[(size_t)l31 * S + ko]);
        const bf16x8 b0 = *reinterpret_cast<const bf16x8*>(&pET[(size_t)(nbase + l31) * S + ko]);
        const bf16x8 b1 = *reinterpret_cast<const bf16x8*>(&pET[(size_t)(nbase + 32 + l31) * S + ko]);
        acc0 = __builtin_amdgcn_mfma_f32_32x32x16_bf16(a, b0, acc0, 0, 0, 0);
        acc1 = __builtin_amdgcn_mfma_f32_32x32x16_bf16(a, b1, acc1, 0, 0, 0);
    }

    float part0 = 0.f, part1 = 0.f;
#pragma unroll
    for (int reg = 0; reg < 16; reg++) {
        const int c = (reg & 3) + 8 * (reg >> 2) + 4 * half;
        const float o0 = acc0[reg];
        const float o1 = acc1[reg];
        __builtin_nontemporal_store(__logf(o0), &out2[((size_t)t * C + c) * N + nbase + l31]);
        __builtin_nontemporal_store(__logf(o1), &out2[((size_t)t * C + c) * N + nbase + 32 + l31]);
        part0 = fmaf(sw[c], o0, part0);
        part1 = fmaf(sw[c], o1, part1);
    }
    part0 += __shfl_xor(part0, 32, 64);
    part1 += __shfl_xor(part1, 32, 64);
    if (half == 0) {
        __builtin_nontemporal_store(__logf(part0), &out1[(size_t)t * N + nbase + l31]);
        __builtin_nontemporal_store(__logf(part1), &out1[(size_t)t * N + nbase + 32 + l31]);
    }
}

// ---------------------------------------------------------------------------
extern "C" void kernel_launch(void* const* d_in, const int* in_sizes, int n_in,
                              void* d_out, int out_size, void* d_ws, size_t ws_size,
                              hipStream_t stream) {
    const float* in_init  = (const float*)d_in[0];  // [C,S]
    const float* in_cw    = (const float*)d_in[1];  // [T,C]
    const float* in_emis  = (const float*)d_in[2];  // [S,N]
    const float* in_trans = (const float*)d_in[3];  // [S,S]

    float* out = (float*)d_out;

    // Workspace layout (~9.5 MB, 256B aligned)
    char* wsb = (char*)d_ws;
    float*  ws_pcw = (float*)(wsb);                                  // 64 KB [T,C]
    __bf16* ws_pET = (__bf16*)(wsb + (64u << 10));                   // 1 MB  [N,S]
    __bf16* ws_Hhi = (__bf16*)(wsb + (1088u << 10));                 // 4 MB  [T,C,S]
    __bf16* ws_Hlo = (__bf16*)(wsb + (5184u << 10));                 // 4 MB  [T,C,S]
    __bf16* Pslot[2][4];
    for (int sl = 0; sl < 2; sl++)
        for (int pl = 0; pl < 4; pl++)
            Pslot[sl][pl] = (__bf16*)(wsb + (9280u << 10) + (size_t)(sl * 4 + pl) * (32u << 10));

    // 1) All softmaxes in one launch.
    fused_softmax_kernel<<<352, 256, 0, stream>>>(
        in_emis, in_cw, in_trans, in_init,
        out + OFF3, out + OFF4, out + OFF5,
        ws_pET, ws_pcw,
        Pslot[0][0], Pslot[0][1], Pslot[0][2], Pslot[0][3],
        ws_Hhi, ws_Hlo);

    // 2) Whole H-doubling chain in one cooperative kernel (9 internal rounds).
    {
        __bf16 *r0hi = Pslot[0][0], *r0lo = Pslot[0][1], *t0hi = Pslot[0][2], *t0lo = Pslot[0][3];
        __bf16 *r1hi = Pslot[1][0], *r1lo = Pslot[1][1], *t1hi = Pslot[1][2], *t1lo = Pslot[1][3];
        __bf16 *hhi = ws_Hhi, *hlo = ws_Hlo;
        float* o3 = out + OFF3;
        void* args[] = {&r0hi, &r0lo, &t0hi, &t0lo,
                        &r1hi, &r1lo, &t1hi, &t1lo,
                        &hhi, &hlo, &o3};
        hipLaunchCooperativeKernel((const void*)chain_coop_kernel,
                                   dim3(264), dim3(256), args, 0, stream);
    }

    // 3) Observation GEMM (32x32 MFMA) + fused logs + chain reduction.
    obs_mfma_kernel<<<dim3(N / 256, T), 256, 0, stream>>>(ws_Hhi, ws_pET, ws_pcw,
                                                          out + OFF1, out + OFF2);
}

// Round 5
// 413.770 us; speedup vs baseline: 1.6265x; 1.6265x over previous
//
#include <hip/hip_runtime.h>
#include <hip/hip_bf16.h>
#include <cmath>

// Problem constants (fixed by setup_inputs)
constexpr int S = 128;   // num_states
constexpr int C = 32;    // num_chains
constexpr int N = 4096;  // num_nodes
constexpr int T = 512;   // num_iters

// Output layout (flat float32, concatenated in reference return order)
constexpr size_t OFF1 = 0;                          // log_observed_state_probs  [T,N]
constexpr size_t OFF2 = OFF1 + (size_t)T * N;       // log_observed_state_probs_ [T,C,N]
constexpr size_t OFF3 = OFF2 + (size_t)T * C * N;   // log_hidden_state_probs   [T,C,S]
constexpr size_t OFF4 = OFF3 + (size_t)T * C * S;   // log_emission             [S,N]
constexpr size_t OFF5 = OFF4 + (size_t)S * N;       // log_chain_weights        [T,C]

typedef __bf16 bf16x8 __attribute__((ext_vector_type(8)));
typedef float floatx4 __attribute__((ext_vector_type(4)));
typedef float floatx16 __attribute__((ext_vector_type(16)));

__device__ __forceinline__ void split_bf16(float p, __bf16& hi, __bf16& lo) {
    hi = (__bf16)p;
    lo = (__bf16)(p - (float)hi);
}

// ---------------------------------------------------------------------------
// Fused softmax kernel, one launch, 352 blocks x 256 threads:
//   [0,128)   emission rows (4096 cols): log->out4, bf16 transposed -> pET[N,S]
//   [128,256) transition rows (128 cols): hi/lo pair row-major (R) + transposed (T)
//   [256,288) init rows (128 cols): log->out3[t=0], hi/lo pair -> Hhi/Hlo[t=0]
//   [288,352) chain weights, 8 rows/block of 32 cols: log->out5, fp32 -> pcw
// ---------------------------------------------------------------------------
__global__ __launch_bounds__(256) void fused_softmax_kernel(
        const float* __restrict__ emis, const float* __restrict__ cw,
        const float* __restrict__ trans, const float* __restrict__ init,
        float* __restrict__ out3, float* __restrict__ out4, float* __restrict__ out5,
        __bf16* __restrict__ pET, float* __restrict__ pcw,
        __bf16* __restrict__ Rhi, __bf16* __restrict__ Rlo,
        __bf16* __restrict__ Thi, __bf16* __restrict__ Tlo,
        __bf16* __restrict__ Hhi, __bf16* __restrict__ Hlo) {
    const int b = blockIdx.x;
    const int tid = threadIdx.x;

    if (b >= 288) {   // ---- chain weights: 8 rows of 32 per block ----
        const int row = (b - 288) * 8 + (tid >> 5);
        const int j = tid & 31;
        const float v = cw[(size_t)row * C + j];
        float m = v;
#pragma unroll
        for (int o = 16; o > 0; o >>= 1) m = fmaxf(m, __shfl_xor(m, o, 64));
        float s = __expf(v - m);
#pragma unroll
        for (int o = 16; o > 0; o >>= 1) s += __shfl_xor(s, o, 64);
        const float lv = v - m - __logf(s);
        out5[(size_t)row * C + j] = lv;
        pcw[(size_t)row * C + j] = __expf(lv);
        return;
    }

    const float* x;
    int cols, row;
    if (b < 128)      { row = b;       cols = N; x = emis  + (size_t)row * N; }
    else if (b < 256) { row = b - 128; cols = S; x = trans + (size_t)row * S; }
    else              { row = b - 256; cols = S; x = init  + (size_t)row * S; }

    __shared__ float sm[4];
    __shared__ float ss[4];

    float m = -INFINITY;
    for (int j = tid; j < cols; j += 256) m = fmaxf(m, x[j]);
#pragma unroll
    for (int o = 32; o > 0; o >>= 1) m = fmaxf(m, __shfl_xor(m, o, 64));
    const int wid = tid >> 6;
    if ((tid & 63) == 0) sm[wid] = m;
    __syncthreads();
    m = fmaxf(fmaxf(sm[0], sm[1]), fmaxf(sm[2], sm[3]));

    float s = 0.f;
    for (int j = tid; j < cols; j += 256) s += __expf(x[j] - m);
#pragma unroll
    for (int o = 32; o > 0; o >>= 1) s += __shfl_xor(s, o, 64);
    if ((tid & 63) == 0) ss[wid] = s;
    __syncthreads();
    s = ss[0] + ss[1] + ss[2] + ss[3];
    const float lse = m + __logf(s);

    for (int j = tid; j < cols; j += 256) {
        const float v = x[j] - lse;
        const float p = __expf(v);
        if (b < 128) {
            out4[(size_t)row * N + j] = v;
            pET[(size_t)j * S + row] = (__bf16)p;
        } else if (b < 256) {
            __bf16 hi, lo; split_bf16(p, hi, lo);
            Rhi[(size_t)row * S + j] = hi; Rlo[(size_t)row * S + j] = lo;
            Thi[(size_t)j * S + row] = hi; Tlo[(size_t)j * S + row] = lo;
        } else {
            out3[((size_t)0 * C + row) * S + j] = v;
            __bf16 hi, lo; split_bf16(p, hi, lo);
            Hhi[(size_t)row * S + j] = hi; Hlo[(size_t)row * S + j] = lo;
        }
    }
}

// ---------------------------------------------------------------------------
// One H-doubling round (m = 2^(r-1)), hi/lo bf16 pair MFMA (3 MFMAs per
// product -> ~fp32 accuracy). [R3-proven version: ~40 us for all 9 launches;
// cooperative grid.sync variant measured 300 us -- do NOT re-fuse.]
//   blocks [0, count):       H_{m+b} = H_b * P^m   (+ pair store + log->out3)
//   blocks [count, count+8): P^{2m}  = P^m * P^m   (16 rows each, both layouts)
// ---------------------------------------------------------------------------
__global__ __launch_bounds__(256) void h_round_kernel(
        const __bf16* __restrict__ Rhi, const __bf16* __restrict__ Rlo,
        const __bf16* __restrict__ Thi, const __bf16* __restrict__ Tlo,
        __bf16* __restrict__ Rnhi, __bf16* __restrict__ Rnlo,
        __bf16* __restrict__ Tnhi, __bf16* __restrict__ Tnlo,
        __bf16* __restrict__ Hhi, __bf16* __restrict__ Hlo,
        float* __restrict__ out3, int m, int count) {
    const int b = blockIdx.x;
    const int w = threadIdx.x >> 6;
    const int lane = threadIdx.x & 63;
    const int lr = lane & 15;
    const int quad = lane >> 4;

    if (b < count) {
        const __bf16* Ahi = Hhi + (size_t)b * C * S;
        const __bf16* Alo = Hlo + (size_t)b * C * S;
        floatx4 acc[2][2];
#pragma unroll
        for (int mt = 0; mt < 2; mt++)
#pragma unroll
            for (int nt = 0; nt < 2; nt++) acc[mt][nt] = (floatx4)0.f;

#pragma unroll
        for (int kt = 0; kt < 4; kt++) {
            const int ko = kt * 32 + quad * 8;
            const bf16x8 ah0 = *reinterpret_cast<const bf16x8*>(&Ahi[(size_t)lr * S + ko]);
            const bf16x8 ah1 = *reinterpret_cast<const bf16x8*>(&Ahi[(size_t)(16 + lr) * S + ko]);
            const bf16x8 al0 = *reinterpret_cast<const bf16x8*>(&Alo[(size_t)lr * S + ko]);
            const bf16x8 al1 = *reinterpret_cast<const bf16x8*>(&Alo[(size_t)(16 + lr) * S + ko]);
            const bf16x8 bh0 = *reinterpret_cast<const bf16x8*>(&Thi[(size_t)(w * 32 + lr) * S + ko]);
            const bf16x8 bh1 = *reinterpret_cast<const bf16x8*>(&Thi[(size_t)(w * 32 + 16 + lr) * S + ko]);
            const bf16x8 bl0 = *reinterpret_cast<const bf16x8*>(&Tlo[(size_t)(w * 32 + lr) * S + ko]);
            const bf16x8 bl1 = *reinterpret_cast<const bf16x8*>(&Tlo[(size_t)(w * 32 + 16 + lr) * S + ko]);
            acc[0][0] = __builtin_amdgcn_mfma_f32_16x16x32_bf16(ah0, bh0, acc[0][0], 0, 0, 0);
            acc[0][0] = __builtin_amdgcn_mfma_f32_16x16x32_bf16(ah0, bl0, acc[0][0], 0, 0, 0);
            acc[0][0] = __builtin_amdgcn_mfma_f32_16x16x32_bf16(al0, bh0, acc[0][0], 0, 0, 0);
            acc[0][1] = __builtin_amdgcn_mfma_f32_16x16x32_bf16(ah0, bh1, acc[0][1], 0, 0, 0);
            acc[0][1] = __builtin_amdgcn_mfma_f32_16x16x32_bf16(ah0, bl1, acc[0][1], 0, 0, 0);
            acc[0][1] = __builtin_amdgcn_mfma_f32_16x16x32_bf16(al0, bh1, acc[0][1], 0, 0, 0);
            acc[1][0] = __builtin_amdgcn_mfma_f32_16x16x32_bf16(ah1, bh0, acc[1][0], 0, 0, 0);
            acc[1][0] = __builtin_amdgcn_mfma_f32_16x16x32_bf16(ah1, bl0, acc[1][0], 0, 0, 0);
            acc[1][0] = __builtin_amdgcn_mfma_f32_16x16x32_bf16(al1, bh0, acc[1][0], 0, 0, 0);
            acc[1][1] = __builtin_amdgcn_mfma_f32_16x16x32_bf16(ah1, bh1, acc[1][1], 0, 0, 0);
            acc[1][1] = __builtin_amdgcn_mfma_f32_16x16x32_bf16(ah1, bl1, acc[1][1], 0, 0, 0);
            acc[1][1] = __builtin_amdgcn_mfma_f32_16x16x32_bf16(al1, bh1, acc[1][1], 0, 0, 0);
        }

        const size_t t = (size_t)m + b;
#pragma unroll
        for (int mt = 0; mt < 2; mt++) {
#pragma unroll
            for (int nt = 0; nt < 2; nt++) {
#pragma unroll
                for (int reg = 0; reg < 4; reg++) {
                    const int c = mt * 16 + quad * 4 + reg;
                    const int n = w * 32 + nt * 16 + lr;
                    const float p = acc[mt][nt][reg];
                    __bf16 hi, lo; split_bf16(p, hi, lo);
                    Hhi[(t * C + c) * S + n] = hi;
                    Hlo[(t * C + c) * S + n] = lo;
                    out3[(t * C + c) * S + n] = __logf(p);
                }
            }
        }
    } else {
        const int rb = b - count;
        floatx4 acc[2];
        acc[0] = (floatx4)0.f; acc[1] = (floatx4)0.f;
#pragma unroll
        for (int kt = 0; kt < 4; kt++) {
            const int ko = kt * 32 + quad * 8;
            const bf16x8 ah = *reinterpret_cast<const bf16x8*>(&Rhi[(size_t)(rb * 16 + lr) * S + ko]);
            const bf16x8 al = *reinterpret_cast<const bf16x8*>(&Rlo[(size_t)(rb * 16 + lr) * S + ko]);
            const bf16x8 bh0 = *reinterpret_cast<const bf16x8*>(&Thi[(size_t)(w * 32 + lr) * S + ko]);
            const bf16x8 bh1 = *reinterpret_cast<const bf16x8*>(&Thi[(size_t)(w * 32 + 16 + lr) * S + ko]);
            const bf16x8 bl0 = *reinterpret_cast<const bf16x8*>(&Tlo[(size_t)(w * 32 + lr) * S + ko]);
            const bf16x8 bl1 = *reinterpret_cast<const bf16x8*>(&Tlo[(size_t)(w * 32 + 16 + lr) * S + ko]);
            acc[0] = __builtin_amdgcn_mfma_f32_16x16x32_bf16(ah, bh0, acc[0], 0, 0, 0);
            acc[0] = __builtin_amdgcn_mfma_f32_16x16x32_bf16(ah, bl0, acc[0], 0, 0, 0);
            acc[0] = __builtin_amdgcn_mfma_f32_16x16x32_bf16(al, bh0, acc[0], 0, 0, 0);
            acc[1] = __builtin_amdgcn_mfma_f32_16x16x32_bf16(ah, bh1, acc[1], 0, 0, 0);
            acc[1] = __builtin_amdgcn_mfma_f32_16x16x32_bf16(ah, bl1, acc[1], 0, 0, 0);
            acc[1] = __builtin_amdgcn_mfma_f32_16x16x32_bf16(al, bh1, acc[1], 0, 0, 0);
        }
#pragma unroll
        for (int nt = 0; nt < 2; nt++) {
#pragma unroll
            for (int reg = 0; reg < 4; reg++) {
                const int row = rb * 16 + quad * 4 + reg;
                const int col = w * 32 + nt * 16 + lr;
                const float p = acc[nt][reg];
                __bf16 hi, lo; split_bf16(p, hi, lo);
                Rnhi[(size_t)row * S + col] = hi; Rnlo[(size_t)row * S + col] = lo;
                Tnhi[(size_t)col * S + row] = hi; Tnlo[(size_t)col * S + row] = lo;
            }
        }
    }
}

// ---------------------------------------------------------------------------
// Observation GEMM via 32x32x16 MFMA + LDS-transposed streaming epilogue.
// Block: one t, 256 n-cols; 4 waves, each wave a 32(c) x 64(n) tile as two
// 32x32 accumulators. Raw O staged in LDS [32][260]; then each wave streams
// full 1KB rows of log(O) as global_store_dwordx4 (fully coalesced).
//   out2[t,c,n] = log(O[c,n]);  out1[t,n] = log(sum_c pcw[t,c]*O[c,n])
// ---------------------------------------------------------------------------
__global__ __launch_bounds__(256) void obs_mfma_kernel(
        const __bf16* __restrict__ Hb,    // [T,C,S] (hi plane)
        const __bf16* __restrict__ pET,   // [N,S]
        const float* __restrict__ pcw,    // [T,C]
        float* __restrict__ out1,
        float* __restrict__ out2) {
    constexpr int PITCH = 260;            // fp32 pitch; 260%8==4 -> half-wave bank shift
    __shared__ float tile[C * PITCH];     // 33,280 B raw O staging
    __shared__ float sw[C];

    const int t = blockIdx.y;
    const int tid = threadIdx.x;
    const int w = tid >> 6;
    const int lane = tid & 63;
    const int l31 = lane & 31;
    const int half = lane >> 5;
    const int nwave = w * 64;                       // wave's n-offset in tile
    const int nblk = blockIdx.x * 256;              // block's n-offset global

    if (tid < C) sw[tid] = pcw[(size_t)t * C + tid];
    __syncthreads();

    const __bf16* A = Hb + (size_t)t * C * S;

    floatx16 acc0 = (floatx16)0.f;
    floatx16 acc1 = (floatx16)0.f;

#pragma unroll
    for (int ks = 0; ks < 8; ks++) {
        const int ko = ks * 16 + half * 8;
        const bf16x8 a  = *reinterpret_cast<const bf16x8*>(&A[(size_t)l31 * S + ko]);
        const bf16x8 b0 = *reinterpret_cast<const bf16x8*>(&pET[(size_t)(nblk + nwave + l31) * S + ko]);
        const bf16x8 b1 = *reinterpret_cast<const bf16x8*>(&pET[(size_t)(nblk + nwave + 32 + l31) * S + ko]);
        acc0 = __builtin_amdgcn_mfma_f32_32x32x16_bf16(a, b0, acc0, 0, 0, 0);
        acc1 = __builtin_amdgcn_mfma_f32_32x32x16_bf16(a, b1, acc1, 0, 0, 0);
    }

    // out1 partial sums from raw acc; stage raw O into LDS.
    float part0 = 0.f, part1 = 0.f;
#pragma unroll
    for (int reg = 0; reg < 16; reg++) {
        const int c = (reg & 3) + 8 * (reg >> 2) + 4 * half;
        const float o0 = acc0[reg];
        const float o1 = acc1[reg];
        tile[c * PITCH + nwave + l31]      = o0;
        tile[c * PITCH + nwave + 32 + l31] = o1;
        part0 = fmaf(sw[c], o0, part0);
        part1 = fmaf(sw[c], o1, part1);
    }
    part0 += __shfl_xor(part0, 32, 64);
    part1 += __shfl_xor(part1, 32, 64);
    if (half == 0) {
        out1[(size_t)t * N + nblk + nwave + l31]      = __logf(part0);
        out1[(size_t)t * N + nblk + nwave + 32 + l31] = __logf(part1);
    }
    __syncthreads();

    // Stream out2: each iteration a wave writes one full 1KB row segment.
    const float4* tile4 = reinterpret_cast<const float4*>(tile);
#pragma unroll
    for (int i = 0; i < 8; i++) {
        const int idx = i * 256 + tid;    // 0..2047 float4 slots
        const int c = idx >> 6;           // 0..31
        const int q = idx & 63;           // float4 col in row
        const float4 v = tile4[c * (PITCH / 4) + q];
        float4 lg;
        lg.x = __logf(v.x); lg.y = __logf(v.y);
        lg.z = __logf(v.z); lg.w = __logf(v.w);
        *reinterpret_cast<float4*>(&out2[((size_t)t * C + c) * N + nblk + q * 4]) = lg;
    }
}

// ---------------------------------------------------------------------------
extern "C" void kernel_launch(void* const* d_in, const int* in_sizes, int n_in,
                              void* d_out, int out_size, void* d_ws, size_t ws_size,
                              hipStream_t stream) {
    const float* in_init  = (const float*)d_in[0];  // [C,S]
    const float* in_cw    = (const float*)d_in[1];  // [T,C]
    const float* in_emis  = (const float*)d_in[2];  // [S,N]
    const float* in_trans = (const float*)d_in[3];  // [S,S]

    float* out = (float*)d_out;

    // Workspace layout (~9.5 MB, 256B aligned)
    char* wsb = (char*)d_ws;
    float*  ws_pcw = (float*)(wsb);                                  // 64 KB [T,C]
    __bf16* ws_pET = (__bf16*)(wsb + (64u << 10));                   // 1 MB  [N,S]
    __bf16* ws_Hhi = (__bf16*)(wsb + (1088u << 10));                 // 4 MB  [T,C,S]
    __bf16* ws_Hlo = (__bf16*)(wsb + (5184u << 10));                 // 4 MB  [T,C,S]
    __bf16* Pslot[2][4];
    for (int sl = 0; sl < 2; sl++)
        for (int pl = 0; pl < 4; pl++)
            Pslot[sl][pl] = (__bf16*)(wsb + (9280u << 10) + (size_t)(sl * 4 + pl) * (32u << 10));

    // 1) All softmaxes in one launch.
    fused_softmax_kernel<<<352, 256, 0, stream>>>(
        in_emis, in_cw, in_trans, in_init,
        out + OFF3, out + OFF4, out + OFF5,
        ws_pET, ws_pcw,
        Pslot[0][0], Pslot[0][1], Pslot[0][2], Pslot[0][3],
        ws_Hhi, ws_Hlo);

    // 2) H-doubling rounds (hi/lo-pair MFMA), 9 separate launches (proven
    //    ~40 us total; cooperative-sync variant was 300 us).
    for (int r = 1; r <= 9; r++) {
        const int m = 1 << (r - 1);
        const int count = (m < T - m) ? m : (T - m);
        const int s = (r - 1) & 1, d = r & 1;
        const int extra = (r < 9) ? 8 : 0;
        h_round_kernel<<<count + extra, 256, 0, stream>>>(
            Pslot[s][0], Pslot[s][1], Pslot[s][2], Pslot[s][3],
            Pslot[d][0], Pslot[d][1], Pslot[d][2], Pslot[d][3],
            ws_Hhi, ws_Hlo, out + OFF3, m, count);
    }

    // 3) Observation GEMM (32x32 MFMA) + LDS-transposed streaming epilogue.
    obs_mfma_kernel<<<dim3(N / 256, T), 256, 0, stream>>>(ws_Hhi, ws_pET, ws_pcw,
                                                          out + OFF1, out + OFF2);
}

// Round 6
// 374.554 us; speedup vs baseline: 1.7968x; 1.1047x over previous
//
#include <hip/hip_runtime.h>
#include <hip/hip_bf16.h>
#include <cmath>

// Problem constants (fixed by setup_inputs)
constexpr int S = 128;   // num_states
constexpr int C = 32;    // num_chains
constexpr int N = 4096;  // num_nodes
constexpr int T = 512;   // num_iters

// Output layout (flat float32, concatenated in reference return order)
constexpr size_t OFF1 = 0;                          // log_observed_state_probs  [T,N]
constexpr size_t OFF2 = OFF1 + (size_t)T * N;       // log_observed_state_probs_ [T,C,N]
constexpr size_t OFF3 = OFF2 + (size_t)T * C * N;   // log_hidden_state_probs   [T,C,S]
constexpr size_t OFF4 = OFF3 + (size_t)T * C * S;   // log_emission             [S,N]
constexpr size_t OFF5 = OFF4 + (size_t)S * N;       // log_chain_weights        [T,C]

typedef __bf16 bf16x8 __attribute__((ext_vector_type(8)));
typedef float floatx4 __attribute__((ext_vector_type(4)));
typedef float floatx16 __attribute__((ext_vector_type(16)));

__device__ __forceinline__ void split_bf16(float p, __bf16& hi, __bf16& lo) {
    hi = (__bf16)p;
    lo = (__bf16)(p - (float)hi);
}

// ---------------------------------------------------------------------------
// Fused softmax kernel, one launch, 352 blocks x 256 threads (unchanged).
// ---------------------------------------------------------------------------
__global__ __launch_bounds__(256) void fused_softmax_kernel(
        const float* __restrict__ emis, const float* __restrict__ cw,
        const float* __restrict__ trans, const float* __restrict__ init,
        float* __restrict__ out3, float* __restrict__ out4, float* __restrict__ out5,
        __bf16* __restrict__ pET, float* __restrict__ pcw,
        __bf16* __restrict__ Rhi, __bf16* __restrict__ Rlo,
        __bf16* __restrict__ Thi, __bf16* __restrict__ Tlo,
        __bf16* __restrict__ Hhi, __bf16* __restrict__ Hlo) {
    const int b = blockIdx.x;
    const int tid = threadIdx.x;

    if (b >= 288) {   // ---- chain weights: 8 rows of 32 per block ----
        const int row = (b - 288) * 8 + (tid >> 5);
        const int j = tid & 31;
        const float v = cw[(size_t)row * C + j];
        float m = v;
#pragma unroll
        for (int o = 16; o > 0; o >>= 1) m = fmaxf(m, __shfl_xor(m, o, 64));
        float s = __expf(v - m);
#pragma unroll
        for (int o = 16; o > 0; o >>= 1) s += __shfl_xor(s, o, 64);
        const float lv = v - m - __logf(s);
        out5[(size_t)row * C + j] = lv;
        pcw[(size_t)row * C + j] = __expf(lv);
        return;
    }

    const float* x;
    int cols, row;
    if (b < 128)      { row = b;       cols = N; x = emis  + (size_t)row * N; }
    else if (b < 256) { row = b - 128; cols = S; x = trans + (size_t)row * S; }
    else              { row = b - 256; cols = S; x = init  + (size_t)row * S; }

    __shared__ float sm[4];
    __shared__ float ss[4];

    float m = -INFINITY;
    for (int j = tid; j < cols; j += 256) m = fmaxf(m, x[j]);
#pragma unroll
    for (int o = 32; o > 0; o >>= 1) m = fmaxf(m, __shfl_xor(m, o, 64));
    const int wid = tid >> 6;
    if ((tid & 63) == 0) sm[wid] = m;
    __syncthreads();
    m = fmaxf(fmaxf(sm[0], sm[1]), fmaxf(sm[2], sm[3]));

    float s = 0.f;
    for (int j = tid; j < cols; j += 256) s += __expf(x[j] - m);
#pragma unroll
    for (int o = 32; o > 0; o >>= 1) s += __shfl_xor(s, o, 64);
    if ((tid & 63) == 0) ss[wid] = s;
    __syncthreads();
    s = ss[0] + ss[1] + ss[2] + ss[3];
    const float lse = m + __logf(s);

    for (int j = tid; j < cols; j += 256) {
        const float v = x[j] - lse;
        const float p = __expf(v);
        if (b < 128) {
            out4[(size_t)row * N + j] = v;
            pET[(size_t)j * S + row] = (__bf16)p;
        } else if (b < 256) {
            __bf16 hi, lo; split_bf16(p, hi, lo);
            Rhi[(size_t)row * S + j] = hi; Rlo[(size_t)row * S + j] = lo;
            Thi[(size_t)j * S + row] = hi; Tlo[(size_t)j * S + row] = lo;
        } else {
            out3[((size_t)0 * C + row) * S + j] = v;
            __bf16 hi, lo; split_bf16(p, hi, lo);
            Hhi[(size_t)row * S + j] = hi; Hlo[(size_t)row * S + j] = lo;
        }
    }
}

// ---------------------------------------------------------------------------
// One H-doubling round (m = 2^(r-1)), hi/lo bf16 pair MFMA. [R3-proven:
// ~42 us for all 9 launches; cooperative grid.sync variant measured 300 us.]
// ---------------------------------------------------------------------------
__global__ __launch_bounds__(256) void h_round_kernel(
        const __bf16* __restrict__ Rhi, const __bf16* __restrict__ Rlo,
        const __bf16* __restrict__ Thi, const __bf16* __restrict__ Tlo,
        __bf16* __restrict__ Rnhi, __bf16* __restrict__ Rnlo,
        __bf16* __restrict__ Tnhi, __bf16* __restrict__ Tnlo,
        __bf16* __restrict__ Hhi, __bf16* __restrict__ Hlo,
        float* __restrict__ out3, int m, int count) {
    const int b = blockIdx.x;
    const int w = threadIdx.x >> 6;
    const int lane = threadIdx.x & 63;
    const int lr = lane & 15;
    const int quad = lane >> 4;

    if (b < count) {
        const __bf16* Ahi = Hhi + (size_t)b * C * S;
        const __bf16* Alo = Hlo + (size_t)b * C * S;
        floatx4 acc[2][2];
#pragma unroll
        for (int mt = 0; mt < 2; mt++)
#pragma unroll
            for (int nt = 0; nt < 2; nt++) acc[mt][nt] = (floatx4)0.f;

#pragma unroll
        for (int kt = 0; kt < 4; kt++) {
            const int ko = kt * 32 + quad * 8;
            const bf16x8 ah0 = *reinterpret_cast<const bf16x8*>(&Ahi[(size_t)lr * S + ko]);
            const bf16x8 ah1 = *reinterpret_cast<const bf16x8*>(&Ahi[(size_t)(16 + lr) * S + ko]);
            const bf16x8 al0 = *reinterpret_cast<const bf16x8*>(&Alo[(size_t)lr * S + ko]);
            const bf16x8 al1 = *reinterpret_cast<const bf16x8*>(&Alo[(size_t)(16 + lr) * S + ko]);
            const bf16x8 bh0 = *reinterpret_cast<const bf16x8*>(&Thi[(size_t)(w * 32 + lr) * S + ko]);
            const bf16x8 bh1 = *reinterpret_cast<const bf16x8*>(&Thi[(size_t)(w * 32 + 16 + lr) * S + ko]);
            const bf16x8 bl0 = *reinterpret_cast<const bf16x8*>(&Tlo[(size_t)(w * 32 + lr) * S + ko]);
            const bf16x8 bl1 = *reinterpret_cast<const bf16x8*>(&Tlo[(size_t)(w * 32 + 16 + lr) * S + ko]);
            acc[0][0] = __builtin_amdgcn_mfma_f32_16x16x32_bf16(ah0, bh0, acc[0][0], 0, 0, 0);
            acc[0][0] = __builtin_amdgcn_mfma_f32_16x16x32_bf16(ah0, bl0, acc[0][0], 0, 0, 0);
            acc[0][0] = __builtin_amdgcn_mfma_f32_16x16x32_bf16(al0, bh0, acc[0][0], 0, 0, 0);
            acc[0][1] = __builtin_amdgcn_mfma_f32_16x16x32_bf16(ah0, bh1, acc[0][1], 0, 0, 0);
            acc[0][1] = __builtin_amdgcn_mfma_f32_16x16x32_bf16(ah0, bl1, acc[0][1], 0, 0, 0);
            acc[0][1] = __builtin_amdgcn_mfma_f32_16x16x32_bf16(al0, bh1, acc[0][1], 0, 0, 0);
            acc[1][0] = __builtin_amdgcn_mfma_f32_16x16x32_bf16(ah1, bh0, acc[1][0], 0, 0, 0);
            acc[1][0] = __builtin_amdgcn_mfma_f32_16x16x32_bf16(ah1, bl0, acc[1][0], 0, 0, 0);
            acc[1][0] = __builtin_amdgcn_mfma_f32_16x16x32_bf16(al1, bh0, acc[1][0], 0, 0, 0);
            acc[1][1] = __builtin_amdgcn_mfma_f32_16x16x32_bf16(ah1, bh1, acc[1][1], 0, 0, 0);
            acc[1][1] = __builtin_amdgcn_mfma_f32_16x16x32_bf16(ah1, bl1, acc[1][1], 0, 0, 0);
            acc[1][1] = __builtin_amdgcn_mfma_f32_16x16x32_bf16(al1, bh1, acc[1][1], 0, 0, 0);
        }

        const size_t t = (size_t)m + b;
#pragma unroll
        for (int mt = 0; mt < 2; mt++) {
#pragma unroll
            for (int nt = 0; nt < 2; nt++) {
#pragma unroll
                for (int reg = 0; reg < 4; reg++) {
                    const int c = mt * 16 + quad * 4 + reg;
                    const int n = w * 32 + nt * 16 + lr;
                    const float p = acc[mt][nt][reg];
                    __bf16 hi, lo; split_bf16(p, hi, lo);
                    Hhi[(t * C + c) * S + n] = hi;
                    Hlo[(t * C + c) * S + n] = lo;
                    out3[(t * C + c) * S + n] = __logf(p);
                }
            }
        }
    } else {
        const int rb = b - count;
        floatx4 acc[2];
        acc[0] = (floatx4)0.f; acc[1] = (floatx4)0.f;
#pragma unroll
        for (int kt = 0; kt < 4; kt++) {
            const int ko = kt * 32 + quad * 8;
            const bf16x8 ah = *reinterpret_cast<const bf16x8*>(&Rhi[(size_t)(rb * 16 + lr) * S + ko]);
            const bf16x8 al = *reinterpret_cast<const bf16x8*>(&Rlo[(size_t)(rb * 16 + lr) * S + ko]);
            const bf16x8 bh0 = *reinterpret_cast<const bf16x8*>(&Thi[(size_t)(w * 32 + lr) * S + ko]);
            const bf16x8 bh1 = *reinterpret_cast<const bf16x8*>(&Thi[(size_t)(w * 32 + 16 + lr) * S + ko]);
            const bf16x8 bl0 = *reinterpret_cast<const bf16x8*>(&Tlo[(size_t)(w * 32 + lr) * S + ko]);
            const bf16x8 bl1 = *reinterpret_cast<const bf16x8*>(&Tlo[(size_t)(w * 32 + 16 + lr) * S + ko]);
            acc[0] = __builtin_amdgcn_mfma_f32_16x16x32_bf16(ah, bh0, acc[0], 0, 0, 0);
            acc[0] = __builtin_amdgcn_mfma_f32_16x16x32_bf16(ah, bl0, acc[0], 0, 0, 0);
            acc[0] = __builtin_amdgcn_mfma_f32_16x16x32_bf16(al, bh0, acc[0], 0, 0, 0);
            acc[1] = __builtin_amdgcn_mfma_f32_16x16x32_bf16(ah, bh1, acc[1], 0, 0, 0);
            acc[1] = __builtin_amdgcn_mfma_f32_16x16x32_bf16(ah, bl1, acc[1], 0, 0, 0);
            acc[1] = __builtin_amdgcn_mfma_f32_16x16x32_bf16(al, bh1, acc[1], 0, 0, 0);
        }
#pragma unroll
        for (int nt = 0; nt < 2; nt++) {
#pragma unroll
            for (int reg = 0; reg < 4; reg++) {
                const int row = rb * 16 + quad * 4 + reg;
                const int col = w * 32 + nt * 16 + lr;
                const float p = acc[nt][reg];
                __bf16 hi, lo; split_bf16(p, hi, lo);
                Rnhi[(size_t)row * S + col] = hi; Rnlo[(size_t)row * S + col] = lo;
                Tnhi[(size_t)col * S + row] = hi; Tnlo[(size_t)col * S + row] = lo;
            }
        }
    }
}

// ---------------------------------------------------------------------------
// Observation GEMM v3: t-batched, LDS-shared B, 512 threads (8 waves).
// Block covers 128 n-cols x 8 t's. pET tile (128 rows x 256B) staged ONCE in
// LDS and reused by all 8 waves across 8 t's -> pET global traffic drops
// 512 MB -> 64 MB; Hb traffic 128 MB. Wave w: n-half nw=(w&1)*64, t-pair
// tg=w>>1. 4 x 32x32x16 accs/wave (~105 VGPR). Nontemporal out-stores keep
// L2 for reads.
//   out2[t,c,n] = log(O[c,n]);  out1[t,n] = log(sum_c pcw[t,c]*O[c,n])
// ---------------------------------------------------------------------------
__global__ __launch_bounds__(512, 4) void obs_mfma_kernel(
        const __bf16* __restrict__ Hb,    // [T,C,S] (hi plane)
        const __bf16* __restrict__ pET,   // [N,S]
        const float* __restrict__ pcw,    // [T,C]
        float* __restrict__ out1,
        float* __restrict__ out2) {
    constexpr int BPITCH = 264;  // bytes per LDS row (256 data + 8 pad)
    __shared__ __align__(16) unsigned char Bs[128 * BPITCH];  // 33 KB
    __shared__ float sw[8][C];

    const int tid = threadIdx.x;
    const int w = tid >> 6;
    const int lane = tid & 63;
    const int l31 = lane & 31;
    const int half = lane >> 5;
    const int nw = (w & 1) * 64;       // wave's n-half within block
    const int tg = w >> 1;             // wave's t-pair index (0..3)
    const int nblk = blockIdx.x * 128;
    const int tbase = blockIdx.y * 8;
    const int t0 = tbase + tg * 2;
    const int t1 = t0 + 1;

    // Stage pET rows [nblk, nblk+128) into LDS (padded pitch, coalesced 16B).
#pragma unroll
    for (int p = 0; p < 4; p++) {
        const int idx = p * 512 + tid;     // 0..2047
        const int row = idx >> 4;          // 0..127
        const int c16 = idx & 15;          // 16B chunk within row
        const float4 v = *reinterpret_cast<const float4*>(
            pET + (size_t)(nblk + row) * S + c16 * 8);
        *reinterpret_cast<float4*>(Bs + row * BPITCH + c16 * 16) = v;
    }
    if (tid < 256) sw[tid >> 5][tid & 31] =
        pcw[(size_t)(tbase + (tid >> 5)) * C + (tid & 31)];
    __syncthreads();

    const __bf16* A0 = Hb + (size_t)t0 * C * S;
    const __bf16* A1 = Hb + (size_t)t1 * C * S;

    floatx16 acc[2][2];   // [t][ntile]
#pragma unroll
    for (int tt = 0; tt < 2; tt++)
#pragma unroll
        for (int nt = 0; nt < 2; nt++) acc[tt][nt] = (floatx16)0.f;

#pragma unroll
    for (int ks = 0; ks < 8; ks++) {
        const int ko = ks * 16 + half * 8;
        const bf16x8 a0 = *reinterpret_cast<const bf16x8*>(&A0[(size_t)l31 * S + ko]);
        const bf16x8 a1 = *reinterpret_cast<const bf16x8*>(&A1[(size_t)l31 * S + ko]);
        const bf16x8 b0 = *reinterpret_cast<const bf16x8*>(Bs + (nw + l31) * BPITCH + ko * 2);
        const bf16x8 b1 = *reinterpret_cast<const bf16x8*>(Bs + (nw + 32 + l31) * BPITCH + ko * 2);
        acc[0][0] = __builtin_amdgcn_mfma_f32_32x32x16_bf16(a0, b0, acc[0][0], 0, 0, 0);
        acc[0][1] = __builtin_amdgcn_mfma_f32_32x32x16_bf16(a0, b1, acc[0][1], 0, 0, 0);
        acc[1][0] = __builtin_amdgcn_mfma_f32_32x32x16_bf16(a1, b0, acc[1][0], 0, 0, 0);
        acc[1][1] = __builtin_amdgcn_mfma_f32_32x32x16_bf16(a1, b1, acc[1][1], 0, 0, 0);
    }

#pragma unroll
    for (int tt = 0; tt < 2; tt++) {
        const int t = t0 + tt;
        float p0 = 0.f, p1 = 0.f;
#pragma unroll
        for (int reg = 0; reg < 16; reg++) {
            const int c = (reg & 3) + 8 * (reg >> 2) + 4 * half;
            const float o0 = acc[tt][0][reg];
            const float o1 = acc[tt][1][reg];
            __builtin_nontemporal_store(__logf(o0),
                &out2[((size_t)t * C + c) * N + nblk + nw + l31]);
            __builtin_nontemporal_store(__logf(o1),
                &out2[((size_t)t * C + c) * N + nblk + nw + 32 + l31]);
            p0 = fmaf(sw[tg * 2 + tt][c], o0, p0);
            p1 = fmaf(sw[tg * 2 + tt][c], o1, p1);
        }
        p0 += __shfl_xor(p0, 32, 64);
        p1 += __shfl_xor(p1, 32, 64);
        if (half == 0) {
            __builtin_nontemporal_store(__logf(p0), &out1[(size_t)t * N + nblk + nw + l31]);
            __builtin_nontemporal_store(__logf(p1), &out1[(size_t)t * N + nblk + nw + 32 + l31]);
        }
    }
}

// ---------------------------------------------------------------------------
extern "C" void kernel_launch(void* const* d_in, const int* in_sizes, int n_in,
                              void* d_out, int out_size, void* d_ws, size_t ws_size,
                              hipStream_t stream) {
    const float* in_init  = (const float*)d_in[0];  // [C,S]
    const float* in_cw    = (const float*)d_in[1];  // [T,C]
    const float* in_emis  = (const float*)d_in[2];  // [S,N]
    const float* in_trans = (const float*)d_in[3];  // [S,S]

    float* out = (float*)d_out;

    // Workspace layout (~9.5 MB, 256B aligned)
    char* wsb = (char*)d_ws;
    float*  ws_pcw = (float*)(wsb);                                  // 64 KB [T,C]
    __bf16* ws_pET = (__bf16*)(wsb + (64u << 10));                   // 1 MB  [N,S]
    __bf16* ws_Hhi = (__bf16*)(wsb + (1088u << 10));                 // 4 MB  [T,C,S]
    __bf16* ws_Hlo = (__bf16*)(wsb + (5184u << 10));                 // 4 MB  [T,C,S]
    __bf16* Pslot[2][4];
    for (int sl = 0; sl < 2; sl++)
        for (int pl = 0; pl < 4; pl++)
            Pslot[sl][pl] = (__bf16*)(wsb + (9280u << 10) + (size_t)(sl * 4 + pl) * (32u << 10));

    // 1) All softmaxes in one launch.
    fused_softmax_kernel<<<352, 256, 0, stream>>>(
        in_emis, in_cw, in_trans, in_init,
        out + OFF3, out + OFF4, out + OFF5,
        ws_pET, ws_pcw,
        Pslot[0][0], Pslot[0][1], Pslot[0][2], Pslot[0][3],
        ws_Hhi, ws_Hlo);

    // 2) H-doubling rounds (hi/lo-pair MFMA), 9 separate launches (proven
    //    ~42 us total; cooperative-sync variant was 300 us).
    for (int r = 1; r <= 9; r++) {
        const int m = 1 << (r - 1);
        const int count = (m < T - m) ? m : (T - m);
        const int s = (r - 1) & 1, d = r & 1;
        const int extra = (r < 9) ? 8 : 0;
        h_round_kernel<<<count + extra, 256, 0, stream>>>(
            Pslot[s][0], Pslot[s][1], Pslot[s][2], Pslot[s][3],
            Pslot[d][0], Pslot[d][1], Pslot[d][2], Pslot[d][3],
            ws_Hhi, ws_Hlo, out + OFF3, m, count);
    }

    // 3) Observation GEMM v3: t-batched, LDS-shared B, nontemporal stores.
    obs_mfma_kernel<<<dim3(N / 128, T / 8), 512, 0, stream>>>(
        ws_Hhi, ws_pET, ws_pcw, out + OFF1, out + OFF2);
}